// Round 3
// baseline (920.027 us; speedup 1.0000x reference)
//
#include <hip/hip_runtime.h>

#define LAMC    10000.0f
#define INV_LAM 1e-4f
#define EPSC    1e-12f
#define TOLC    1e-6f
#define BLK     256
#define PBGRID  2048   // phase-B blocks (grid-stride)

// sign(phi(t)) without sqrt: phi = L - R*sqrt(q), q >= EPS > 0
__device__ __forceinline__ bool phi_pos(float t, float A, float p, float N, float b) {
    float q  = fmaxf(fmaf(t, fmaf(t, A, -2.0f * p), N), EPSC);
    float L  = fmaf(-t, A, p);        // p - t*A   (U_MAX = 1)
    float R  = fmaf(t, INV_LAM, b);   // b + t/LAM
    float L2 = L * L;
    float Rq = (R * R) * q;
    return (R < 0.0f) ? ((L >= 0.0f) || (L2 < Rq))
                      : ((L >  0.0f) && (L2 > Rq));
}

// branch-3 solve. Tight bracket: phi has a unique sign change;
//  - p>0, R(p/A)>=0 : phi(p/A) = -R*nrm <= 0       -> root in (0, p/A]
//  - p>0, R(p/A)<0  : phi(p/A) > 0, phi(-lam*b)<0  -> root in (p/A, -lam*b)
//  - p<=0 (=> b<0)  : phi(-lam*b) = L < 0          -> root in (0, -lam*b)
__device__ __forceinline__ float2 heavy_solve(float ux, float uy,
                                              float ax, float ay, float b) {
    float A = fmaf(ax, ax, ay * ay);
    float p = fmaf(ax, ux, ay * uy);
    float N = fmaf(ux, ux, uy * uy);
    float t3;
    if (phi_pos(0.0f, A, p, N, b)) {
        float lo, hi;
        if (p > 0.0f) {
            float tA = p / fmaxf(A, 1e-30f);
            if (fmaf(tA, INV_LAM, b) >= 0.0f) { lo = 0.0f; hi = tA; }
            else                              { lo = tA;  hi = -LAMC * b; }
        } else {
            lo = 0.0f; hi = -LAMC * b;
        }
        #pragma unroll 1
        for (int k = 0; k < 12; ++k) {
            float mid = 0.5f * (lo + hi);
            bool pos = phi_pos(mid, A, p, N, b);
            lo = pos ? mid : lo;
            hi = pos ? hi : mid;
        }
        t3 = 0.5f * (lo + hi);
        #pragma unroll
        for (int k = 0; k < 5; ++k) {          // safeguarded Newton
            float q   = fmaxf(fmaf(t3, fmaf(t3, A, -2.0f * p), N), EPSC);
            float nrm = sqrtf(q);
            float R   = fmaf(t3, INV_LAM, b);
            float f   = fmaf(-t3, A, p) - R * nrm;
            float df  = -A - nrm * INV_LAM - R * fmaf(t3, A, -p) / nrm;
            df = (fabsf(df) > 1e-8f) ? df : -1e-8f;
            bool fp = f > 0.0f;                // phi(t3)>0 -> root above t3
            lo = fp ? t3 : lo;
            hi = fp ? hi : t3;
            t3 = fminf(fmaxf(t3 - f / df, lo), hi);
        }
    } else {
        // reference: bisection collapses to 0, then 3 unclamped Newton steps
        t3 = 0.0f;
        #pragma unroll
        for (int k = 0; k < 3; ++k) {
            float q   = fmaxf(fmaf(t3, fmaf(t3, A, -2.0f * p), N), EPSC);
            float nrm = sqrtf(q);
            float R   = fmaf(t3, INV_LAM, b);
            float f   = fmaf(-t3, A, p) - R * nrm;
            float df  = -A - nrm * INV_LAM - R * fmaf(t3, A, -p) / nrm;
            df = (fabsf(df) > 1e-8f) ? df : -1e-8f;
            t3 = t3 - f / df;
        }
    }
    float q3  = fmaxf(fmaf(t3, fmaf(t3, A, -2.0f * p), N), EPSC);
    float k3  = fmaxf(sqrtf(q3), 1.0f);
    float inv = 1.0f / k3;
    return make_float2(fmaf(-t3, ax, ux) * inv, fmaf(-t3, ay, uy) * inv);
}

// easy paths; returns true if row is heavy (branch 3). ox/oy always set.
__device__ __forceinline__ bool easy_row(float ux, float uy,
                                         float px, float py, float vx, float vy,
                                         float& ox, float& oy) {
    float ax = -2.0f * px, ay = -2.0f * py;
    float h  = fmaf(px, px, py * py) - 1.0f;
    float b  = fmaf(2.0f, h, -2.0f * fmaf(px, vx, py * vy));
    float A  = fmaf(ax, ax, ay * ay);
    float p  = fmaf(ax, ux, ay * uy);
    float n  = sqrtf(fmaxf(fmaf(ux, ux, uy * uy), EPSC));
    float s1 = fminf(1.0f, 1.0f / n);
    float u1x = ux * s1, u1y = uy * s1;
    ox = u1x; oy = u1y;
    if (fmaf(ax, u1x, ay * u1y) <= b + TOLC) return false;
    float t2  = LAMC * (p - b) / fmaf(LAMC, A, 1.0f);
    float u2x = fmaf(-t2, ax, ux), u2y = fmaf(-t2, ay, uy);
    if (t2 >= -TOLC && fmaf(u2x, u2x, u2y * u2y) <= 1.0f + TOLC) {
        ox = u2x; oy = u2y; return false;
    }
    return true;
}

// wave-aggregated worklist push (one global atomic per wave)
__device__ __forceinline__ void push_row(int* cnt, int* ids, bool heavy, int row) {
    unsigned long long m = __ballot(heavy);
    if (m == 0ull) return;
    int lane   = threadIdx.x & 63;
    int leader = __ffsll(m) - 1;
    int total  = __popcll(m);
    int base   = 0;
    if (lane == leader) base = atomicAdd(cnt, total);
    base = __shfl(base, leader);
    if (heavy) {
        int ofs = __popcll(m & ((1ull << lane) - 1ull));
        ids[base + ofs] = row;
    }
}

__global__ __launch_bounds__(BLK) void zero_cnt(int* cnt) {
    if (threadIdx.x == 0 && blockIdx.x == 0) *cnt = 0;
}

__global__ __launch_bounds__(BLK) void phaseA_g(const float4* __restrict__ u4,
                                                const float4* __restrict__ obs4,
                                                float4* __restrict__ out4,
                                                int* __restrict__ cnt,
                                                int* __restrict__ ids,
                                                int npair) {
    int i = blockIdx.x * BLK + threadIdx.x;
    bool valid = i < npair;
    float4 u  = make_float4(0.f, 0.f, 0.f, 0.f);
    float4 o0 = u, o1 = u, o2 = u;
    if (valid) {
        u  = u4[i];
        o0 = obs4[3 * i + 0];
        o1 = obs4[3 * i + 1];
        o2 = obs4[3 * i + 2];
    }
    float4 r = make_float4(0.f, 0.f, 0.f, 0.f);
    bool h0 = false, h1 = false;
    if (valid) {
        h0 = easy_row(u.x, u.y, o0.z, o0.w, o1.x, o1.y, r.x, r.y);
        h1 = easy_row(u.z, u.w, o2.x, o2.y, o2.z, o2.w, r.z, r.w);
    }
    push_row(cnt, ids, h0, 2 * i);
    push_row(cnt, ids, h1, 2 * i + 1);
    if (valid) out4[i] = r;   // heavy rows overwritten by phase B
}

__global__ __launch_bounds__(BLK) void phaseB_g(const float2* __restrict__ u2v,
                                                const float* __restrict__ obs,
                                                float2* __restrict__ out2,
                                                const int* __restrict__ cnt,
                                                const int* __restrict__ ids) {
    int M = *cnt;
    for (int j = blockIdx.x * BLK + threadIdx.x; j < M; j += PBGRID * BLK) {
        int r = ids[j];
        float2 u  = u2v[r];
        float2 pr = *(const float2*)(obs + 6 * r + 2);
        float2 v  = *(const float2*)(obs + 6 * r + 4);
        float ax = -2.0f * pr.x, ay = -2.0f * pr.y;
        float h  = fmaf(pr.x, pr.x, pr.y * pr.y) - 1.0f;
        float b  = fmaf(2.0f, h, -2.0f * fmaf(pr.x, v.x, pr.y * v.y));
        out2[r] = heavy_solve(u.x, u.y, ax, ay, b);
    }
}

// fallback: single kernel, per-thread inline heavy path (used only if ws too small)
__global__ __launch_bounds__(BLK) void cbf_fallback(const float4* __restrict__ u4,
                                                    const float4* __restrict__ obs4,
                                                    float4* __restrict__ out4,
                                                    int npair) {
    int i = blockIdx.x * BLK + threadIdx.x;
    if (i >= npair) return;
    float4 u  = u4[i];
    float4 o0 = obs4[3 * i + 0];
    float4 o1 = obs4[3 * i + 1];
    float4 o2 = obs4[3 * i + 2];
    float4 r;
    if (easy_row(u.x, u.y, o0.z, o0.w, o1.x, o1.y, r.x, r.y)) {
        float2 s = heavy_solve(u.x, u.y, -2.0f * o0.z, -2.0f * o0.w,
                               fmaf(2.0f, fmaf(o0.z, o0.z, o0.w * o0.w) - 1.0f,
                                    -2.0f * fmaf(o0.z, o1.x, o0.w * o1.y)));
        r.x = s.x; r.y = s.y;
    }
    if (easy_row(u.z, u.w, o2.x, o2.y, o2.z, o2.w, r.z, r.w)) {
        float2 s = heavy_solve(u.z, u.w, -2.0f * o2.x, -2.0f * o2.y,
                               fmaf(2.0f, fmaf(o2.x, o2.x, o2.y * o2.y) - 1.0f,
                                    -2.0f * fmaf(o2.x, o2.z, o2.y * o2.w)));
        r.z = s.x; r.w = s.y;
    }
    out4[i] = r;
}

extern "C" void kernel_launch(void* const* d_in, const int* in_sizes, int n_in,
                              void* d_out, int out_size, void* d_ws, size_t ws_size,
                              hipStream_t stream) {
    const float* u_nom = (const float*)d_in[0];
    const float* obs   = (const float*)d_in[1];
    float* out = (float*)d_out;
    int rows   = in_sizes[0] / 2;     // B
    int npair  = rows / 2;            // 2 rows per thread in phase A
    int blocks = (npair + BLK - 1) / BLK;

    size_t need = 64 + (size_t)rows * sizeof(int);   // counter + worst-case ids
    if (ws_size >= need) {
        int* cnt = (int*)d_ws;
        int* ids = (int*)((char*)d_ws + 64);
        zero_cnt<<<1, BLK, 0, stream>>>(cnt);
        phaseA_g<<<blocks, BLK, 0, stream>>>((const float4*)u_nom,
                                             (const float4*)obs,
                                             (float4*)out, cnt, ids, npair);
        phaseB_g<<<PBGRID, BLK, 0, stream>>>((const float2*)u_nom, obs,
                                             (float2*)out, cnt, ids);
    } else {
        cbf_fallback<<<blocks, BLK, 0, stream>>>((const float4*)u_nom,
                                                 (const float4*)obs,
                                                 (float4*)out, npair);
    }
}

// Round 4
// 180.640 us; speedup vs baseline: 5.0932x; 5.0932x over previous
//
#include <hip/hip_runtime.h>

#define LAMC    10000.0f
#define INV_LAM 1e-4f
#define EPSC    1e-12f
#define TOLC    1e-6f
#define BLK     256
#define WPB     (BLK / 64)   // waves per block

// sign(phi(t)) without sqrt: phi = L - R*sqrt(q), q >= EPS > 0
__device__ __forceinline__ bool phi_pos(float t, float A, float p, float N, float b) {
    float q  = fmaxf(fmaf(t, fmaf(t, A, -2.0f * p), N), EPSC);
    float L  = fmaf(-t, A, p);        // p - t*A   (U_MAX = 1)
    float R  = fmaf(t, INV_LAM, b);   // b + t/LAM
    float L2 = L * L;
    float Rq = (R * R) * q;
    return (R < 0.0f) ? ((L >= 0.0f) || (L2 < Rq))
                      : ((L >  0.0f) && (L2 > Rq));
}

// branch-3 solve with proven tight bracket (phi has a unique sign change):
//  - p>0, R(p/A)>=0 : phi(p/A) = -R*nrm <= 0          -> root in (0, p/A]
//  - p>0, R(p/A)<0  : phi(p/A) > 0 and phi(-lam*b) =
//                     L(-lam*b) = p + lam*A*b < 0      -> root in (p/A, -lam*b)
//    (R(p/A)<0 <=> p + lam*A*b < 0, so the endpoint sign is guaranteed)
//  - p<=0 (=> b<0)  : phi(-lam*b) = L < 0              -> root in (0, -lam*b)
__device__ __forceinline__ float2 heavy_solve(float ux, float uy,
                                              float ax, float ay, float b) {
    float A = fmaf(ax, ax, ay * ay);
    float p = fmaf(ax, ux, ay * uy);
    float N = fmaf(ux, ux, uy * uy);
    float t3;
    if (phi_pos(0.0f, A, p, N, b)) {
        float lo, hi;
        if (p > 0.0f) {
            float tA = p / fmaxf(A, 1e-30f);
            if (fmaf(tA, INV_LAM, b) >= 0.0f) { lo = 0.0f; hi = tA; }
            else                              { lo = tA;  hi = -LAMC * b; }
        } else {
            lo = 0.0f; hi = -LAMC * b;
        }
        #pragma unroll 1
        for (int k = 0; k < 12; ++k) {
            float mid = 0.5f * (lo + hi);
            bool pos = phi_pos(mid, A, p, N, b);
            lo = pos ? mid : lo;
            hi = pos ? hi : mid;
        }
        t3 = 0.5f * (lo + hi);
        #pragma unroll
        for (int k = 0; k < 5; ++k) {          // safeguarded Newton
            float q   = fmaxf(fmaf(t3, fmaf(t3, A, -2.0f * p), N), EPSC);
            float nrm = sqrtf(q);
            float R   = fmaf(t3, INV_LAM, b);
            float f   = fmaf(-t3, A, p) - R * nrm;
            float df  = -A - nrm * INV_LAM - R * fmaf(t3, A, -p) / nrm;
            df = (fabsf(df) > 1e-8f) ? df : -1e-8f;
            bool fp = f > 0.0f;                // phi(t3)>0 -> root above t3
            lo = fp ? t3 : lo;
            hi = fp ? hi : t3;
            t3 = fminf(fmaxf(t3 - f / df, lo), hi);
        }
    } else {
        // reference: bisection collapses to 0, then 3 unclamped Newton steps
        t3 = 0.0f;
        #pragma unroll
        for (int k = 0; k < 3; ++k) {
            float q   = fmaxf(fmaf(t3, fmaf(t3, A, -2.0f * p), N), EPSC);
            float nrm = sqrtf(q);
            float R   = fmaf(t3, INV_LAM, b);
            float f   = fmaf(-t3, A, p) - R * nrm;
            float df  = -A - nrm * INV_LAM - R * fmaf(t3, A, -p) / nrm;
            df = (fabsf(df) > 1e-8f) ? df : -1e-8f;
            t3 = t3 - f / df;
        }
    }
    float q3  = fmaxf(fmaf(t3, fmaf(t3, A, -2.0f * p), N), EPSC);
    float k3  = fmaxf(sqrtf(q3), 1.0f);
    float inv = 1.0f / k3;
    return make_float2(fmaf(-t3, ax, ux) * inv, fmaf(-t3, ay, uy) * inv);
}

// easy paths (decision math bit-identical to the passing rounds);
// returns true if row is heavy (branch 3). ox/oy always set for easy rows.
__device__ __forceinline__ bool easy_row(float ux, float uy,
                                         float px, float py, float vx, float vy,
                                         float& ox, float& oy) {
    float ax = -2.0f * px, ay = -2.0f * py;
    float h  = fmaf(px, px, py * py) - 1.0f;
    float b  = fmaf(2.0f, h, -2.0f * fmaf(px, vx, py * vy));
    float A  = fmaf(ax, ax, ay * ay);
    float p  = fmaf(ax, ux, ay * uy);
    float n  = sqrtf(fmaxf(fmaf(ux, ux, uy * uy), EPSC));
    float s1 = fminf(1.0f, 1.0f / n);
    float u1x = ux * s1, u1y = uy * s1;
    ox = u1x; oy = u1y;
    if (fmaf(ax, u1x, ay * u1y) <= b + TOLC) return false;
    float t2  = LAMC * (p - b) / fmaf(LAMC, A, 1.0f);
    float u2x = fmaf(-t2, ax, ux), u2y = fmaf(-t2, ay, uy);
    if (t2 >= -TOLC && fmaf(u2x, u2x, u2y * u2y) <= 1.0f + TOLC) {
        ox = u2x; oy = u2y; return false;
    }
    return true;
}

__global__ __launch_bounds__(BLK) void cbf_kernel(const float4* __restrict__ u4,
                                                  const float4* __restrict__ obs4,
                                                  const float2* __restrict__ u2v,
                                                  const float*  __restrict__ obs,
                                                  float4* __restrict__ out4,
                                                  int npair) {
    __shared__ short  sid[WPB][128];    // wave-local heavy worklist (row ids)
    __shared__ float2 sres[WPB][128];   // wave-local heavy results by local row

    int tid  = threadIdx.x;
    int wave = tid >> 6;
    int lane = tid & 63;
    unsigned long long ltmask = (1ull << lane) - 1ull;

    int i = blockIdx.x * BLK + tid;
    bool valid = i < npair;
    float4 u  = make_float4(0.f, 0.f, 0.f, 0.f);
    float4 o0 = u, o1 = u, o2 = u;
    if (valid) {
        u  = u4[i];
        o0 = obs4[3 * i + 0];
        o1 = obs4[3 * i + 1];
        o2 = obs4[3 * i + 2];
    }
    // row 2i:   p=(o0.z,o0.w)  v=(o1.x,o1.y)
    // row 2i+1: p=(o2.x,o2.y)  v=(o2.z,o2.w)
    float4 r = make_float4(0.f, 0.f, 0.f, 0.f);
    bool h0 = false, h1 = false;
    if (valid) {
        h0 = easy_row(u.x, u.y, o0.z, o0.w, o1.x, o1.y, r.x, r.y);
        h1 = easy_row(u.z, u.w, o2.x, o2.y, o2.z, o2.w, r.z, r.w);
    }

    // wave-local ballot compaction — no atomics, no block barriers
    unsigned long long m0 = __ballot(h0);
    unsigned long long m1 = __ballot(h1);
    int c0  = __popcll(m0);
    int tot = c0 + __popcll(m1);
    if (h0) sid[wave][__popcll(m0 & ltmask)]      = (short)(2 * lane);
    if (h1) sid[wave][c0 + __popcll(m1 & ltmask)] = (short)(2 * lane + 1);
    __threadfence_block();   // wave lockstep + lgkmcnt drain orders LDS w->r

    int rowbase = blockIdx.x * (2 * BLK) + wave * 128;
    #pragma unroll 1
    for (int j = lane; j < tot; j += 64) {
        int lr = sid[wave][j];
        int gr = rowbase + lr;
        float2 uu = u2v[gr];                               // L1/L2-hot
        float2 pr = *(const float2*)(obs + 6 * gr + 2);
        float2 vv = *(const float2*)(obs + 6 * gr + 4);
        float ax = -2.0f * pr.x, ay = -2.0f * pr.y;
        float h  = fmaf(pr.x, pr.x, pr.y * pr.y) - 1.0f;
        float b  = fmaf(2.0f, h, -2.0f * fmaf(pr.x, vv.x, pr.y * vv.y));
        sres[wave][lr] = heavy_solve(uu.x, uu.y, ax, ay, b);
    }
    __threadfence_block();

    if (h0) { float2 s = sres[wave][2 * lane];     r.x = s.x; r.y = s.y; }
    if (h1) { float2 s = sres[wave][2 * lane + 1]; r.z = s.x; r.w = s.y; }
    if (valid) out4[i] = r;
}

extern "C" void kernel_launch(void* const* d_in, const int* in_sizes, int n_in,
                              void* d_out, int out_size, void* d_ws, size_t ws_size,
                              hipStream_t stream) {
    const float* u_nom = (const float*)d_in[0];
    const float* obs   = (const float*)d_in[1];
    float* out = (float*)d_out;
    int rows   = in_sizes[0] / 2;     // B
    int npair  = rows / 2;            // 2 rows per thread
    int blocks = (npair + BLK - 1) / BLK;
    cbf_kernel<<<blocks, BLK, 0, stream>>>((const float4*)u_nom,
                                           (const float4*)obs,
                                           (const float2*)u_nom, obs,
                                           (float4*)out, npair);
}

// Round 6
// 180.374 us; speedup vs baseline: 5.1007x; 1.0015x over previous
//
#include <hip/hip_runtime.h>

#define LAMC    10000.0f
#define INV_LAM 1e-4f
#define EPSC    1e-12f
#define TOLC    1e-6f
#define BLK     256
#define WPB     (BLK / 64)   // waves per block

__device__ __forceinline__ float frcp(float x)  { return __builtin_amdgcn_rcpf(x); }
__device__ __forceinline__ float frsq(float x)  { return __builtin_amdgcn_rsqf(x); }
__device__ __forceinline__ float fsqrt_(float x){ return __builtin_amdgcn_sqrtf(x); }

// sign(phi(t)) without sqrt/div: phi = L - R*sqrt(q), q >= EPS > 0
__device__ __forceinline__ bool phi_pos(float t, float A, float p, float N, float b) {
    float q  = fmaxf(fmaf(t, fmaf(t, A, -2.0f * p), N), EPSC);
    float L  = fmaf(-t, A, p);        // p - t*A   (U_MAX = 1)
    float R  = fmaf(t, INV_LAM, b);   // b + t/LAM
    float L2 = L * L;
    float Rq = (R * R) * q;
    return (R < 0.0f) ? ((L >= 0.0f) || (L2 < Rq))
                      : ((L >  0.0f) && (L2 > Rq));
}

// branch-3 solve with proven tight bracket (phi has a unique sign change):
//  - p>0, R(p/A)>=0 : phi(p/A) <= 0                    -> root in (0, p/A]
//  - p>0, R(p/A)<0  : phi(p/A) > 0, phi(-lam*b) < 0    -> root in (p/A, -lam*b)
//  - p<=0 (=> b<0)  : phi(-lam*b) = L < 0              -> root in (0, -lam*b)
// 12 bisections + 5 safeguarded Newton = fully converged in fp32.
__device__ __forceinline__ float2 heavy_solve(float ux, float uy,
                                              float ax, float ay, float b) {
    float A = fmaf(ax, ax, ay * ay);
    float p = fmaf(ax, ux, ay * uy);
    float N = fmaf(ux, ux, uy * uy);
    float t3;
    if (phi_pos(0.0f, A, p, N, b)) {
        float lo, hi;
        if (p > 0.0f) {
            float tA = p * frcp(fmaxf(A, 1e-30f));
            if (fmaf(tA, INV_LAM, b) >= 0.0f) { lo = 0.0f; hi = tA; }
            else                              { lo = tA;  hi = -LAMC * b; }
        } else {
            lo = 0.0f; hi = -LAMC * b;
        }
        #pragma unroll 1
        for (int k = 0; k < 12; ++k) {
            float mid = 0.5f * (lo + hi);
            bool pos = phi_pos(mid, A, p, N, b);
            lo = pos ? mid : lo;
            hi = pos ? hi : mid;
        }
        t3 = 0.5f * (lo + hi);
        #pragma unroll
        for (int k = 0; k < 5; ++k) {          // safeguarded Newton
            float q   = fmaxf(fmaf(t3, fmaf(t3, A, -2.0f * p), N), EPSC);
            float nrm = fsqrt_(q);
            float R   = fmaf(t3, INV_LAM, b);
            float f   = fmaf(-t3, A, p) - R * nrm;
            float df  = -A - nrm * INV_LAM - R * fmaf(t3, A, -p) * frcp(nrm);
            df = (fabsf(df) > 1e-8f) ? df : -1e-8f;
            bool fp = f > 0.0f;                // phi(t3)>0 -> root above t3
            lo = fp ? t3 : lo;
            hi = fp ? hi : t3;
            t3 = fminf(fmaxf(t3 - f * frcp(df), lo), hi);
        }
    } else {
        // reference: bisection collapses to 0, then 3 unclamped Newton steps
        t3 = 0.0f;
        #pragma unroll
        for (int k = 0; k < 3; ++k) {
            float q   = fmaxf(fmaf(t3, fmaf(t3, A, -2.0f * p), N), EPSC);
            float nrm = fsqrt_(q);
            float R   = fmaf(t3, INV_LAM, b);
            float f   = fmaf(-t3, A, p) - R * nrm;
            float df  = -A - nrm * INV_LAM - R * fmaf(t3, A, -p) * frcp(nrm);
            df = (fabsf(df) > 1e-8f) ? df : -1e-8f;
            t3 = t3 - f * frcp(df);
        }
    }
    float q3  = fmaxf(fmaf(t3, fmaf(t3, A, -2.0f * p), N), EPSC);
    float k3  = fmaxf(fsqrt_(q3), 1.0f);
    float inv = frcp(k3);
    return make_float2(fmaf(-t3, ax, ux) * inv, fmaf(-t3, ay, uy) * inv);
}

// easy paths; returns true if row is heavy (branch 3). ox/oy always set.
__device__ __forceinline__ bool easy_row(float ux, float uy,
                                         float px, float py, float vx, float vy,
                                         float& ox, float& oy) {
    float ax = -2.0f * px, ay = -2.0f * py;
    float h  = fmaf(px, px, py * py) - 1.0f;
    float b  = fmaf(2.0f, h, -2.0f * fmaf(px, vx, py * vy));
    float A  = fmaf(ax, ax, ay * ay);
    float p  = fmaf(ax, ux, ay * uy);
    float N  = fmaf(ux, ux, uy * uy);
    float s1 = fminf(1.0f, frsq(fmaxf(N, EPSC)));   // min(1, 1/|u|)
    float u1x = ux * s1, u1y = uy * s1;
    ox = u1x; oy = u1y;
    if (fmaf(ax, u1x, ay * u1y) <= b + TOLC) return false;
    float t2  = LAMC * (p - b) * frcp(fmaf(LAMC, A, 1.0f));
    float u2x = fmaf(-t2, ax, ux), u2y = fmaf(-t2, ay, uy);
    if (t2 >= -TOLC && fmaf(u2x, u2x, u2y * u2y) <= 1.0f + TOLC) {
        ox = u2x; oy = u2y; return false;
    }
    return true;
}

__global__ __launch_bounds__(BLK) void cbf_kernel(const float4* __restrict__ u4,
                                                  const float4* __restrict__ obs4,
                                                  const float2* __restrict__ u2v,
                                                  const float*  __restrict__ obs,
                                                  float4* __restrict__ out4,
                                                  int npair) {
    __shared__ short  sid[WPB][128];    // wave-local heavy worklist (row ids)
    __shared__ float2 sres[WPB][128];   // wave-local heavy results by local row

    int tid  = threadIdx.x;
    int wave = tid >> 6;
    int lane = tid & 63;
    unsigned long long ltmask = (1ull << lane) - 1ull;

    int i = blockIdx.x * BLK + tid;
    bool valid = i < npair;
    float4 u  = make_float4(0.f, 0.f, 0.f, 0.f);
    float4 o0 = u, o1 = u, o2 = u;
    if (valid) {
        u  = u4[i];
        o0 = obs4[3 * i + 0];
        o1 = obs4[3 * i + 1];
        o2 = obs4[3 * i + 2];
    }
    // row 2i:   p=(o0.z,o0.w)  v=(o1.x,o1.y)
    // row 2i+1: p=(o2.x,o2.y)  v=(o2.z,o2.w)
    float4 r = make_float4(0.f, 0.f, 0.f, 0.f);
    bool h0 = false, h1 = false;
    if (valid) {
        h0 = easy_row(u.x, u.y, o0.z, o0.w, o1.x, o1.y, r.x, r.y);
        h1 = easy_row(u.z, u.w, o2.x, o2.y, o2.z, o2.w, r.z, r.w);
    }

    // wave-local ballot compaction — no atomics, no block barriers
    unsigned long long m0 = __ballot(h0);
    unsigned long long m1 = __ballot(h1);
    int c0  = __popcll(m0);
    int tot = c0 + __popcll(m1);
    if (h0) sid[wave][__popcll(m0 & ltmask)]      = (short)(2 * lane);
    if (h1) sid[wave][c0 + __popcll(m1 & ltmask)] = (short)(2 * lane + 1);
    __threadfence_block();   // wave lockstep + lgkmcnt drain orders LDS w->r

    int rowbase = blockIdx.x * (2 * BLK) + wave * 128;
    #pragma unroll 1
    for (int j = lane; j < tot; j += 64) {
        int lr = sid[wave][j];
        int gr = rowbase + lr;
        float2 uu = u2v[gr];                               // L1/L2-hot
        float2 pr = *(const float2*)(obs + 6 * gr + 2);
        float2 vv = *(const float2*)(obs + 6 * gr + 4);
        float ax = -2.0f * pr.x, ay = -2.0f * pr.y;
        float h  = fmaf(pr.x, pr.x, pr.y * pr.y) - 1.0f;
        float b  = fmaf(2.0f, h, -2.0f * fmaf(pr.x, vv.x, pr.y * vv.y));
        sres[wave][lr] = heavy_solve(uu.x, uu.y, ax, ay, b);
    }
    __threadfence_block();

    if (h0) { float2 s = sres[wave][2 * lane];     r.x = s.x; r.y = s.y; }
    if (h1) { float2 s = sres[wave][2 * lane + 1]; r.z = s.x; r.w = s.y; }
    if (valid) out4[i] = r;
}

extern "C" void kernel_launch(void* const* d_in, const int* in_sizes, int n_in,
                              void* d_out, int out_size, void* d_ws, size_t ws_size,
                              hipStream_t stream) {
    const float* u_nom = (const float*)d_in[0];
    const float* obs   = (const float*)d_in[1];
    float* out = (float*)d_out;
    int rows   = in_sizes[0] / 2;     // B
    int npair  = rows / 2;            // 2 rows per thread
    int blocks = (npair + BLK - 1) / BLK;
    cbf_kernel<<<blocks, BLK, 0, stream>>>((const float4*)u_nom,
                                           (const float4*)obs,
                                           (const float2*)u_nom, obs,
                                           (float4*)out, npair);
}